// Round 1
// baseline (215.509 us; speedup 1.0000x reference)
//
#include <hip/hip_runtime.h>
#include <math.h>

// Problem constants (B=8, T=1024, D=512, LEFT=16, RIGHT=0)
constexpr int Bn = 8;
constexpr int Tn = 1024;
constexpr int Dn = 512;
constexpr int BT = Bn * Tn;      // 8192 rows
constexpr int WIN = 16;          // window size

// ---------------------------------------------------------------------------
// Kernel 1: P = X @ W for W in {M, C, V}, selected by blockIdx.z.
// X: [BT][Dn] row-major f32.  W: [Dn][Dn] row-major f32.  P -> ws slab z.
// Tile: BM=64, BN=64, BK=16; 256 threads; 4x4 per thread. Plain fp32 VALU.
// ---------------------------------------------------------------------------
__global__ __launch_bounds__(256) void gemm_qkv(
    const float* __restrict__ X,
    const float* __restrict__ Mw,
    const float* __restrict__ Cw,
    const float* __restrict__ Vw,
    float* __restrict__ ws)
{
    const float* W = (blockIdx.z == 0) ? Mw : (blockIdx.z == 1) ? Cw : Vw;
    float* P = ws + (size_t)blockIdx.z * BT * Dn;

    __shared__ float As[64][20];   // [m][k], +4 pad to break bank patterns
    __shared__ float Bs[16][64];   // [k][n]

    const int tid = threadIdx.x;
    const int tx = tid & 15;       // 0..15  -> n
    const int ty = tid >> 4;       // 0..15  -> m
    const int bm0 = blockIdx.y * 64;
    const int bn0 = blockIdx.x * 64;

    float acc[4][4] = {};

    for (int k0 = 0; k0 < Dn; k0 += 16) {
        // Load A tile: 64 rows x 16 cols = 1024 floats, 4 per thread (float4)
        {
            const int r = tid >> 2;          // 0..63
            const int c = (tid & 3) * 4;     // 0,4,8,12
            const float4 a = *(const float4*)(X + (size_t)(bm0 + r) * Dn + k0 + c);
            As[r][c + 0] = a.x; As[r][c + 1] = a.y;
            As[r][c + 2] = a.z; As[r][c + 3] = a.w;
        }
        // Load B tile: 16 rows x 64 cols
        {
            const int r = tid >> 4;          // 0..15
            const int c = (tid & 15) * 4;    // 0..60
            *(float4*)&Bs[r][c] = *(const float4*)(W + (size_t)(k0 + r) * Dn + bn0 + c);
        }
        __syncthreads();

        #pragma unroll
        for (int kk = 0; kk < 16; ++kk) {
            float a[4], b[4];
            #pragma unroll
            for (int i = 0; i < 4; ++i) a[i] = As[ty * 4 + i][kk];
            #pragma unroll
            for (int j = 0; j < 4; ++j) b[j] = Bs[kk][tx * 4 + j];
            #pragma unroll
            for (int i = 0; i < 4; ++i)
                #pragma unroll
                for (int j = 0; j < 4; ++j)
                    acc[i][j] += a[i] * b[j];
        }
        __syncthreads();
    }

    #pragma unroll
    for (int i = 0; i < 4; ++i) {
        const int row = bm0 + ty * 4 + i;
        float* p = P + (size_t)row * Dn + bn0 + tx * 4;
        p[0] = acc[i][0]; p[1] = acc[i][1]; p[2] = acc[i][2]; p[3] = acc[i][3];
    }
}

// ---------------------------------------------------------------------------
// Kernel 2: windowed attention. One 64-lane wave per (b,t) token.
// Also copies inputs into out[..., 0:512] (concat).
// Invalid window slots (t-15+w < 0) have logit = 0 exactly (reference zeroes
// the *keys*, so softmax denominator includes exp(0)=1 for them) and
// contribute nothing to the value sum.
// ---------------------------------------------------------------------------
__global__ __launch_bounds__(256) void attn_win(
    const float* __restrict__ X,
    const float* __restrict__ ws,
    float* __restrict__ out)
{
    const float* Q = ws;
    const float* K = ws + (size_t)BT * Dn;
    const float* V = ws + (size_t)2 * BT * Dn;

    const int wid = threadIdx.x >> 6;       // wave in block: 0..3
    const int ln  = threadIdx.x & 63;       // lane
    const int tg  = blockIdx.x * 4 + wid;   // global token 0..8191
    const int b   = tg >> 10;
    const int tt  = tg & 1023;

    // Copy inputs -> out[..., 0:512] (vectorized, coalesced per wave)
    {
        const float4* xin = (const float4*)(X + (size_t)tg * Dn);
        float4* o0 = (float4*)(out + (size_t)tg * (2 * Dn));
        o0[ln * 2]     = xin[ln * 2];
        o0[ln * 2 + 1] = xin[ln * 2 + 1];
    }

    // Q fragment: 8 consecutive floats per lane
    float q[8];
    {
        const float4* qp = (const float4*)(Q + (size_t)tg * Dn);
        const float4 a = qp[ln * 2];
        const float4 c = qp[ln * 2 + 1];
        q[0] = a.x; q[1] = a.y; q[2] = a.z; q[3] = a.w;
        q[4] = c.x; q[5] = c.y; q[6] = c.z; q[7] = c.w;
    }

    float lw[16];
    #pragma unroll
    for (int w = 0; w < WIN; ++w) {
        const int src = tt - (WIN - 1) + w;
        float dot = 0.0f;
        if (src >= 0) {
            const float* krow = K + (size_t)(b * Tn + src) * Dn + ln * 8;
            const float4 k0 = *(const float4*)krow;
            const float4 k1 = *(const float4*)(krow + 4);
            dot = q[0] * k0.x + q[1] * k0.y + q[2] * k0.z + q[3] * k0.w
                + q[4] * k1.x + q[5] * k1.y + q[6] * k1.z + q[7] * k1.w;
        }
        // 64-lane butterfly reduce; every lane ends with the full sum
        #pragma unroll
        for (int s = 32; s > 0; s >>= 1) dot += __shfl_xor(dot, s, 64);
        lw[w] = (src >= 0) ? dot : 0.0f;
    }

    // Softmax over 16 (computed redundantly per lane)
    float mx = lw[0];
    #pragma unroll
    for (int w = 1; w < WIN; ++w) mx = fmaxf(mx, lw[w]);
    float den = 0.0f;
    float sc[16];
    #pragma unroll
    for (int w = 0; w < WIN; ++w) { sc[w] = expf(lw[w] - mx); den += sc[w]; }
    const float inv = 1.0f / den;

    // Weighted sum of V rows; each lane owns 8 output dims
    float acc[8] = {};
    #pragma unroll
    for (int w = 0; w < WIN; ++w) {
        const int src = tt - (WIN - 1) + w;
        if (src >= 0) {
            const float s = sc[w] * inv;
            const float* vrow = V + (size_t)(b * Tn + src) * Dn + ln * 8;
            const float4 v0 = *(const float4*)vrow;
            const float4 v1 = *(const float4*)(vrow + 4);
            acc[0] += s * v0.x; acc[1] += s * v0.y;
            acc[2] += s * v0.z; acc[3] += s * v0.w;
            acc[4] += s * v1.x; acc[5] += s * v1.y;
            acc[6] += s * v1.z; acc[7] += s * v1.w;
        }
    }

    float* o1 = out + (size_t)tg * (2 * Dn) + Dn + ln * 8;
    *(float4*)o1       = make_float4(acc[0], acc[1], acc[2], acc[3]);
    *(float4*)(o1 + 4) = make_float4(acc[4], acc[5], acc[6], acc[7]);
}

// ---------------------------------------------------------------------------
extern "C" void kernel_launch(void* const* d_in, const int* in_sizes, int n_in,
                              void* d_out, int out_size, void* d_ws, size_t ws_size,
                              hipStream_t stream)
{
    const float* X  = (const float*)d_in[0];   // inputs (8,1024,512)
    const float* Mw = (const float*)d_in[1];   // M (512,512)
    const float* Cw = (const float*)d_in[2];   // C (512,512)
    const float* Vw = (const float*)d_in[3];   // V (512,512)
    float* out = (float*)d_out;                // (8,1024,1024)
    float* ws  = (float*)d_ws;                 // need 3*8192*512*4 = 48 MiB

    // Q,K,V projections: grid (N/64, M/64, 3)
    dim3 gg(Dn / 64, BT / 64, 3);
    gemm_qkv<<<gg, 256, 0, stream>>>(X, Mw, Cw, Vw, ws);

    // Windowed attention: 4 waves per block, one wave per token
    attn_win<<<BT / 4, 256, 0, stream>>>(X, ws, out);
}

// Round 2
// 126.950 us; speedup vs baseline: 1.6976x; 1.6976x over previous
//
#include <hip/hip_runtime.h>
#include <math.h>

// Problem constants (B=8, T=1024, D=512, LEFT=16, RIGHT=0)
constexpr int Bn = 8;
constexpr int Tn = 1024;
constexpr int Dn = 512;
constexpr int BT = Bn * Tn;      // 8192 rows
constexpr int WIN = 16;

typedef short bs8 __attribute__((ext_vector_type(8)));     // 8 bf16 (bit pattern)
typedef unsigned short us8 __attribute__((ext_vector_type(8)));
typedef float fx4 __attribute__((ext_vector_type(4)));

// bf16 helpers (self-contained, RNE)
__device__ inline unsigned short f2bf(float f) {
    unsigned int u = __float_as_uint(f);
    u += 0x7FFFu + ((u >> 16) & 1u);
    return (unsigned short)(u >> 16);
}
__device__ inline float bf2f(unsigned short h) {
    return __uint_as_float(((unsigned int)h) << 16);
}

// ---------------------------------------------------------------------------
// Kernel 1: split X (f32) -> A' bf16 [8192][1024] = [hi | lo]
// (the GEMM K-loop re-reads the hi slab for k'>=1024)
// ---------------------------------------------------------------------------
__global__ __launch_bounds__(256) void split_x(const float* __restrict__ X,
                                               short* __restrict__ Ap)
{
    const int i = blockIdx.x * 256 + threadIdx.x;   // 524288 threads
    const int m = i >> 6;
    const int kc = (i & 63) * 8;
    const float4* xp = (const float4*)(X + (size_t)m * Dn + kc);
    const float4 x0 = xp[0], x1 = xp[1];
    const float xs[8] = {x0.x, x0.y, x0.z, x0.w, x1.x, x1.y, x1.z, x1.w};
    union { bs8 v; unsigned short u[8]; } hi, lo;
    #pragma unroll
    for (int j = 0; j < 8; ++j) {
        const float x = xs[j];
        const unsigned short h = f2bf(x);
        hi.u[j] = h;
        lo.u[j] = f2bf(x - bf2f(h));
    }
    short* base = Ap + (size_t)m * 1024 + kc;
    *(bs8*)base         = hi.v;
    *(bs8*)(base + 512) = lo.v;
}

// ---------------------------------------------------------------------------
// Kernel 2: split+transpose weights -> Bt bf16 [1536 n'][1024 k] = [hi | lo]
// n' = z*512 + n  (z: 0=M,1=C,2=V).  W_z is [k][n] row-major.
// ---------------------------------------------------------------------------
__global__ __launch_bounds__(256) void split_w(const float* __restrict__ Mw,
                                               const float* __restrict__ Cw,
                                               const float* __restrict__ Vw,
                                               short* __restrict__ Bt)
{
    __shared__ float tile[64][65];
    const int z = blockIdx.z;
    const float* W = (z == 0) ? Mw : (z == 1) ? Cw : Vw;
    const int k0 = blockIdx.x * 64;
    const int n0 = blockIdx.y * 64;
    const int tid = threadIdx.x;

    #pragma unroll
    for (int rr = 0; rr < 4; ++rr) {
        const int row = (tid >> 4) * 4 + rr;        // 0..63 (k)
        const int col = (tid & 15) * 4;             // 0..60 (n)
        const float4 w = *(const float4*)(W + (size_t)(k0 + row) * Dn + n0 + col);
        tile[row][col + 0] = w.x; tile[row][col + 1] = w.y;
        tile[row][col + 2] = w.z; tile[row][col + 3] = w.w;
    }
    __syncthreads();

    const int n  = tid >> 2;          // 0..63
    const int ks = (tid & 3) * 16;    // 0,16,32,48
    union { bs8 v; unsigned short u[8]; } hi0, hi1, lo0, lo1;
    #pragma unroll
    for (int i = 0; i < 8; ++i) {
        float x = tile[ks + i][n];
        unsigned short h = f2bf(x);
        hi0.u[i] = h; lo0.u[i] = f2bf(x - bf2f(h));
        x = tile[ks + 8 + i][n];
        h = f2bf(x);
        hi1.u[i] = h; lo1.u[i] = f2bf(x - bf2f(h));
    }
    short* base = Bt + (size_t)(z * 512 + n0 + n) * 1024 + k0 + ks;
    *(bs8*)base               = hi0.v;
    *(bs8*)(base + 8)         = hi1.v;
    *(bs8*)(base + 512)       = lo0.v;
    *(bs8*)(base + 512 + 8)   = lo1.v;
}

// ---------------------------------------------------------------------------
// Kernel 3: bf16 MFMA GEMM.  C[8192][1536] = A'[8192][K'=1536] @ B'[K'][1536]
//   K' slabs: [0,512)=AhiBhi  [512,1024)=AloBhi  [1024,1536)=AhiBlo
//   A' stored [m][1024]=[hi|lo]  (k'>=1024 remaps to hi)
//   Bt stored [n'][1024]=[hi|lo] (k'>=512 remaps: hi then lo)
// Output slabs by n': [0,512)=Q -> d_out[...,512:1024] f32
//                     [512,1024)=K -> Kws f32; [1024,1536)=V -> Vws bf16
// 128x128 tile, BK=32, 4 waves x (64x64), mfma_f32_16x16x32_bf16.
// LDS linear-dest global_load_lds + pre-swizzled source; XOR-swizzled ds_read.
// ---------------------------------------------------------------------------
__global__ __launch_bounds__(256) void gemm_mfma(
    const short* __restrict__ Ap, const short* __restrict__ Bt,
    float* __restrict__ outQ, float* __restrict__ Kws,
    unsigned short* __restrict__ Vws)
{
    __shared__ short Asl[128 * 32];   // 8 KB, chunk c=(m*4+j): A[m][kb*8..], kb=j^(m&3)
    __shared__ short Bsl[128 * 32];   // 8 KB, same scheme over n

    // XCD-aware swizzle: 768 blocks = 8 XCDs x 96
    const int lin = blockIdx.y * gridDim.x + blockIdx.x;
    const int swz = (lin & 7) * 96 + (lin >> 3);
    const int nt = swz % 12, mt = swz / 12;
    const int m0 = mt * 128, n0g = nt * 128;

    const int tid = threadIdx.x;
    const int ln  = tid & 63;
    const int wid = tid >> 6;
    const int wr = wid >> 1, wc = wid & 1;
    const int lrow = ln & 15;
    const int lkb  = ln >> 4;                 // k-block 0..3
    const int jsw  = lkb ^ (lrow & 3);        // swizzled chunk sub-index (same for A and B)

    fx4 acc[4][4] = {};

    // Per-thread staging bases (element offsets, k part added per iter)
    int am[2], aj[2];
    size_t abase[2], bbase[2];
    #pragma unroll
    for (int h = 0; h < 2; ++h) {
        const int c = tid + h * 256;
        am[h] = c >> 2;
        aj[h] = (c & 3) ^ (am[h] & 3);        // kb actually staged
        abase[h] = (size_t)(m0  + am[h]) * 1024 + aj[h] * 8;
        bbase[h] = (size_t)(n0g + am[h]) * 1024 + aj[h] * 8;
    }

    for (int k0 = 0; k0 < 1536; k0 += 32) {
        const int ka0 = (k0 < 1024) ? k0 : (k0 - 1024);   // A slab remap
        const int kb0 = (k0 < 512)  ? k0 : (k0 - 512);    // B slab remap
        #pragma unroll
        for (int h = 0; h < 2; ++h) {
            const int c = tid + h * 256;
            __builtin_amdgcn_global_load_lds(
                (const __attribute__((address_space(1))) unsigned int*)(Ap + abase[h] + ka0),
                (__attribute__((address_space(3))) unsigned int*)(Asl + c * 8), 16, 0, 0);
            __builtin_amdgcn_global_load_lds(
                (const __attribute__((address_space(1))) unsigned int*)(Bt + bbase[h] + kb0),
                (__attribute__((address_space(3))) unsigned int*)(Bsl + c * 8), 16, 0, 0);
        }
        __syncthreads();   // compiler drains vmcnt before barrier

        bs8 a[4], b[4];
        #pragma unroll
        for (int mf = 0; mf < 4; ++mf) {
            const int m = wr * 64 + mf * 16 + lrow;
            a[mf] = *(const bs8*)(Asl + (m * 4 + jsw) * 8);
        }
        #pragma unroll
        for (int nf = 0; nf < 4; ++nf) {
            const int n = wc * 64 + nf * 16 + lrow;
            b[nf] = *(const bs8*)(Bsl + (n * 4 + jsw) * 8);
        }
        #pragma unroll
        for (int mf = 0; mf < 4; ++mf)
            #pragma unroll
            for (int nf = 0; nf < 4; ++nf)
                acc[mf][nf] = __builtin_amdgcn_mfma_f32_16x16x32_bf16(
                    a[mf], b[nf], acc[mf][nf], 0, 0, 0);
        __syncthreads();
    }

    // Epilogue: route by output slab (each block entirely within one slab)
    const int slab = n0g >> 9;                 // 0=Q, 1=K, 2=V
    const int cbase = (n0g - slab * 512) + wc * 64;
    #pragma unroll
    for (int mf = 0; mf < 4; ++mf) {
        #pragma unroll
        for (int nf = 0; nf < 4; ++nf) {
            const int col = cbase + nf * 16 + lrow;
            #pragma unroll
            for (int r = 0; r < 4; ++r) {
                const int row = m0 + wr * 64 + mf * 16 + lkb * 4 + r;
                const float v = acc[mf][nf][r];
                if (slab == 0)      outQ[(size_t)row * 1024 + 512 + col] = v;
                else if (slab == 1) Kws[(size_t)row * 512 + col] = v;
                else                Vws[(size_t)row * 512 + col] = f2bf(v);
            }
        }
    }
}

// ---------------------------------------------------------------------------
// Kernel 4: windowed attention. One wave per token. Q read from d_out scratch
// (then overwritten with the answer). K f32, V bf16 from ws.
// Invalid slots (src<0): logit = 0 exactly (exp(0) in denominator), no V term.
// ---------------------------------------------------------------------------
__global__ __launch_bounds__(256) void attn_win(
    const float* __restrict__ X,
    const float* __restrict__ Kws,
    const unsigned short* __restrict__ Vws,
    float* __restrict__ out)
{
    const int wid = threadIdx.x >> 6;
    const int ln  = threadIdx.x & 63;
    const int tg  = blockIdx.x * 4 + wid;
    const int b   = tg >> 10;
    const int tt  = tg & 1023;

    // Copy inputs -> out[..., 0:512]
    {
        const float4* xin = (const float4*)(X + (size_t)tg * Dn);
        float4* o0 = (float4*)(out + (size_t)tg * 1024);
        o0[ln * 2]     = xin[ln * 2];
        o0[ln * 2 + 1] = xin[ln * 2 + 1];
    }

    // Q fragment from d_out[..., 512:1024]
    float q[8];
    {
        const float4* qp = (const float4*)(out + (size_t)tg * 1024 + 512);
        const float4 a = qp[ln * 2];
        const float4 c = qp[ln * 2 + 1];
        q[0] = a.x; q[1] = a.y; q[2] = a.z; q[3] = a.w;
        q[4] = c.x; q[5] = c.y; q[6] = c.z; q[7] = c.w;
    }

    float lw[16];
    #pragma unroll
    for (int w = 0; w < WIN; ++w) {
        const int src = tt - (WIN - 1) + w;
        float dot = 0.0f;
        if (src >= 0) {
            const float* krow = Kws + (size_t)(b * Tn + src) * Dn + ln * 8;
            const float4 k0 = *(const float4*)krow;
            const float4 k1 = *(const float4*)(krow + 4);
            dot = q[0] * k0.x + q[1] * k0.y + q[2] * k0.z + q[3] * k0.w
                + q[4] * k1.x + q[5] * k1.y + q[6] * k1.z + q[7] * k1.w;
        }
        #pragma unroll
        for (int s = 32; s > 0; s >>= 1) dot += __shfl_xor(dot, s, 64);
        lw[w] = (src >= 0) ? dot : 0.0f;
    }

    float mx = lw[0];
    #pragma unroll
    for (int w = 1; w < WIN; ++w) mx = fmaxf(mx, lw[w]);
    float den = 0.0f;
    float sc[16];
    #pragma unroll
    for (int w = 0; w < WIN; ++w) { sc[w] = expf(lw[w] - mx); den += sc[w]; }
    const float inv = 1.0f / den;

    float acc[8] = {};
    #pragma unroll
    for (int w = 0; w < WIN; ++w) {
        const int src = tt - (WIN - 1) + w;
        if (src >= 0) {
            const float s = sc[w] * inv;
            const us8 v = *(const us8*)(Vws + (size_t)(b * Tn + src) * Dn + ln * 8);
            #pragma unroll
            for (int j = 0; j < 8; ++j) acc[j] += s * bf2f(v[j]);
        }
    }

    float* o1 = out + (size_t)tg * 1024 + 512 + ln * 8;
    *(float4*)o1       = make_float4(acc[0], acc[1], acc[2], acc[3]);
    *(float4*)(o1 + 4) = make_float4(acc[4], acc[5], acc[6], acc[7]);
}

// ---------------------------------------------------------------------------
extern "C" void kernel_launch(void* const* d_in, const int* in_sizes, int n_in,
                              void* d_out, int out_size, void* d_ws, size_t ws_size,
                              hipStream_t stream)
{
    const float* X  = (const float*)d_in[0];
    const float* Mw = (const float*)d_in[1];
    const float* Cw = (const float*)d_in[2];
    const float* Vw = (const float*)d_in[3];
    float* out = (float*)d_out;

    // ws layout (43 MB total):
    short* Ap = (short*)d_ws;                                  // 8192*1024 bf16 = 16 MB
    short* Bt = Ap + (size_t)BT * 1024;                        // 1536*1024 bf16 = 3 MB
    float* Kws = (float*)(Bt + (size_t)1536 * 1024);           // 8192*512 f32 = 16 MB
    unsigned short* Vws = (unsigned short*)(Kws + (size_t)BT * Dn); // 8 MB

    split_x<<<(BT * 64) / 256, 256, 0, stream>>>(X, Ap);
    split_w<<<dim3(8, 8, 3), 256, 0, stream>>>(Mw, Cw, Vw, Bt);
    gemm_mfma<<<dim3(12, 64), 256, 0, stream>>>(Ap, Bt, out, Kws, Vws);
    attn_win<<<BT / 4, 256, 0, stream>>>(X, Kws, Vws, out);
}

// Round 3
// 126.796 us; speedup vs baseline: 1.6997x; 1.0012x over previous
//
#include <hip/hip_runtime.h>
#include <math.h>

// Problem constants (B=8, T=1024, D=512, LEFT=16, RIGHT=0)
constexpr int Bn = 8;
constexpr int Tn = 1024;
constexpr int Dn = 512;
constexpr int BT = Bn * Tn;      // 8192 rows
constexpr int WIN = 16;

typedef short bs8 __attribute__((ext_vector_type(8)));     // 8 bf16 (bit pattern)
typedef unsigned short us8 __attribute__((ext_vector_type(8)));
typedef float fx4 __attribute__((ext_vector_type(4)));

// bf16 helpers (self-contained, RNE)
__device__ inline unsigned short f2bf(float f) {
    unsigned int u = __float_as_uint(f);
    u += 0x7FFFu + ((u >> 16) & 1u);
    return (unsigned short)(u >> 16);
}
__device__ inline float bf2f(unsigned short h) {
    return __uint_as_float(((unsigned int)h) << 16);
}

// ---------------------------------------------------------------------------
// Kernel 1: split X (f32) -> A' bf16 [8192][1024] = [hi | lo]
// ---------------------------------------------------------------------------
__global__ __launch_bounds__(256) void split_x(const float* __restrict__ X,
                                               short* __restrict__ Ap)
{
    const int i = blockIdx.x * 256 + threadIdx.x;   // 524288 threads
    const int m = i >> 6;
    const int kc = (i & 63) * 8;
    const float4* xp = (const float4*)(X + (size_t)m * Dn + kc);
    const float4 x0 = xp[0], x1 = xp[1];
    const float xs[8] = {x0.x, x0.y, x0.z, x0.w, x1.x, x1.y, x1.z, x1.w};
    union { bs8 v; unsigned short u[8]; } hi, lo;
    #pragma unroll
    for (int j = 0; j < 8; ++j) {
        const float x = xs[j];
        const unsigned short h = f2bf(x);
        hi.u[j] = h;
        lo.u[j] = f2bf(x - bf2f(h));
    }
    short* base = Ap + (size_t)m * 1024 + kc;
    *(bs8*)base         = hi.v;
    *(bs8*)(base + 512) = lo.v;
}

// ---------------------------------------------------------------------------
// Kernel 2: G = M @ C^T in fp32 (G[a][b] = sum_j M[a,j] C[b,j]), written
// split+transposed into Bt rows [0,512): Bt[b][a]=hi(G[a][b]), Bt[b][512+a]=lo.
// 64x64 tile, both operands row-major along K (coalesced).
// ---------------------------------------------------------------------------
__global__ __launch_bounds__(256) void g_gemm(const float* __restrict__ Mw,
                                              const float* __restrict__ Cw,
                                              short* __restrict__ Bt)
{
    __shared__ float As[64][17];
    __shared__ float Bs[64][17];
    const int a0 = blockIdx.y * 64;
    const int b0 = blockIdx.x * 64;
    const int tid = threadIdx.x;
    const int tx = tid & 15, ty = tid >> 4;

    float acc[4][4] = {};

    for (int j0 = 0; j0 < Dn; j0 += 16) {
        const int r = tid >> 2;
        const int c = (tid & 3) * 4;
        const float4 a = *(const float4*)(Mw + (size_t)(a0 + r) * Dn + j0 + c);
        As[r][c + 0] = a.x; As[r][c + 1] = a.y; As[r][c + 2] = a.z; As[r][c + 3] = a.w;
        const float4 b = *(const float4*)(Cw + (size_t)(b0 + r) * Dn + j0 + c);
        Bs[r][c + 0] = b.x; Bs[r][c + 1] = b.y; Bs[r][c + 2] = b.z; Bs[r][c + 3] = b.w;
        __syncthreads();
        #pragma unroll
        for (int kk = 0; kk < 16; ++kk) {
            float av[4], bv[4];
            #pragma unroll
            for (int i = 0; i < 4; ++i) av[i] = As[ty * 4 + i][kk];
            #pragma unroll
            for (int j = 0; j < 4; ++j) bv[j] = Bs[tx * 4 + j][kk];
            #pragma unroll
            for (int i = 0; i < 4; ++i)
                #pragma unroll
                for (int j = 0; j < 4; ++j)
                    acc[i][j] += av[i] * bv[j];
        }
        __syncthreads();
    }

    #pragma unroll
    for (int i = 0; i < 4; ++i) {
        #pragma unroll
        for (int j = 0; j < 4; ++j) {
            const int a = a0 + ty * 4 + i;      // k index
            const int b = b0 + tx * 4 + j;      // n index (Bt row)
            const float g = acc[i][j];
            const unsigned short h = f2bf(g);
            Bt[(size_t)b * 1024 + a]       = (short)h;
            Bt[(size_t)b * 1024 + 512 + a] = (short)f2bf(g - bf2f(h));
        }
    }
}

// ---------------------------------------------------------------------------
// Kernel 3: split+transpose V weights (hi only) -> Bt rows [512,1024):
// Bt[512+n][k] = hi(V[k][n]).  (lo half of these rows is never read.)
// ---------------------------------------------------------------------------
__global__ __launch_bounds__(256) void split_v(const float* __restrict__ Vw,
                                               short* __restrict__ Bt)
{
    __shared__ float tile[64][65];
    const int k0 = blockIdx.x * 64;
    const int n0 = blockIdx.y * 64;
    const int tid = threadIdx.x;

    #pragma unroll
    for (int rr = 0; rr < 4; ++rr) {
        const int row = (tid >> 4) * 4 + rr;        // k
        const int col = (tid & 15) * 4;             // n
        const float4 w = *(const float4*)(Vw + (size_t)(k0 + row) * Dn + n0 + col);
        tile[row][col + 0] = w.x; tile[row][col + 1] = w.y;
        tile[row][col + 2] = w.z; tile[row][col + 3] = w.w;
    }
    __syncthreads();

    const int n  = tid >> 2;          // 0..63
    const int ks = (tid & 3) * 16;    // 0,16,32,48
    union { bs8 v; unsigned short u[8]; } hi0, hi1;
    #pragma unroll
    for (int i = 0; i < 8; ++i) {
        hi0.u[i] = f2bf(tile[ks + i][n]);
        hi1.u[i] = f2bf(tile[ks + 8 + i][n]);
    }
    short* base = Bt + (size_t)(512 + n0 + n) * 1024 + k0 + ks;
    *(bs8*)base       = hi0.v;
    *(bs8*)(base + 8) = hi1.v;
}

// ---------------------------------------------------------------------------
// Kernel 4: bf16 MFMA GEMM.  [Y | V'] = X @ [G | V]
//   Y slab (n' in [0,512)):  K' = 1536 = AhiGhi + AloGhi + AhiGlo -> f32 to
//                            out[...,512:1024] (scratch, read by attn)
//   V slab (n' in [512,1024)): K' = 512 = AhiVhi only -> bf16 to Vws
//   A' stored [m][1024]=[hi|lo]; Bt stored [n'][1024]=[hi|lo].
// 128x128 tile, BK=32, 4 waves x (64x64), mfma_f32_16x16x32_bf16.
// Grid 512 blocks: xcd=lin&7 -> mt-panel; Y-blocks at low lin (dispatch first).
// ---------------------------------------------------------------------------
__global__ __launch_bounds__(256) void gemm_mfma(
    const short* __restrict__ Ap, const short* __restrict__ Bt,
    float* __restrict__ outY, unsigned short* __restrict__ Vws)
{
    __shared__ short Asl[128 * 32];   // 8 KB; chunk c=(m*4+j): A[m][kb*8..], kb=j^(m&3)
    __shared__ short Bsl[128 * 32];

    const int lin = blockIdx.x;              // 0..511
    const int xcd = lin & 7;
    const int s   = lin >> 3;                // 0..63
    const int nt  = s >> 3;                  // 0..7  (nt<4 -> Y slab, long K)
    const int mt  = xcd * 8 + (s & 7);       // 0..63
    const int m0 = mt * 128, n0g = nt * 128;
    const int slab = nt >> 2;                // 0=Y, 1=V
    const int kEnd = slab ? 512 : 1536;

    const int tid = threadIdx.x;
    const int ln  = tid & 63;
    const int wid = tid >> 6;
    const int wr = wid >> 1, wc = wid & 1;
    const int lrow = ln & 15;
    const int lkb  = ln >> 4;                 // 0..3
    const int jsw  = lkb ^ (lrow & 3);        // swizzled chunk sub-index

    fx4 acc[4][4] = {};

    int am[2], aj[2];
    size_t abase[2], bbase[2];
    #pragma unroll
    for (int h = 0; h < 2; ++h) {
        const int c = tid + h * 256;
        am[h] = c >> 2;
        aj[h] = (c & 3) ^ (am[h] & 3);        // kb actually staged
        abase[h] = (size_t)(m0  + am[h]) * 1024 + aj[h] * 8;
        bbase[h] = (size_t)(n0g + am[h]) * 1024 + aj[h] * 8;
    }

    for (int k0 = 0; k0 < kEnd; k0 += 32) {
        const int ka0 = (k0 < 1024) ? k0 : (k0 - 1024);   // A: hi,lo,hi
        const int kb0 = (k0 < 512)  ? k0 : (k0 - 512);    // B: hi,hi,lo
        #pragma unroll
        for (int h = 0; h < 2; ++h) {
            const int c = tid + h * 256;
            __builtin_amdgcn_global_load_lds(
                (const __attribute__((address_space(1))) unsigned int*)(Ap + abase[h] + ka0),
                (__attribute__((address_space(3))) unsigned int*)(Asl + c * 8), 16, 0, 0);
            __builtin_amdgcn_global_load_lds(
                (const __attribute__((address_space(1))) unsigned int*)(Bt + bbase[h] + kb0),
                (__attribute__((address_space(3))) unsigned int*)(Bsl + c * 8), 16, 0, 0);
        }
        __syncthreads();

        bs8 a[4], b[4];
        #pragma unroll
        for (int mf = 0; mf < 4; ++mf) {
            const int m = wr * 64 + mf * 16 + lrow;
            a[mf] = *(const bs8*)(Asl + (m * 4 + jsw) * 8);
        }
        #pragma unroll
        for (int nf = 0; nf < 4; ++nf) {
            const int n = wc * 64 + nf * 16 + lrow;
            b[nf] = *(const bs8*)(Bsl + (n * 4 + jsw) * 8);
        }
        #pragma unroll
        for (int mf = 0; mf < 4; ++mf)
            #pragma unroll
            for (int nf = 0; nf < 4; ++nf)
                acc[mf][nf] = __builtin_amdgcn_mfma_f32_16x16x32_bf16(
                    a[mf], b[nf], acc[mf][nf], 0, 0, 0);
        __syncthreads();
    }

    const int cbase = (n0g - slab * 512) + wc * 64;
    #pragma unroll
    for (int mf = 0; mf < 4; ++mf) {
        #pragma unroll
        for (int nf = 0; nf < 4; ++nf) {
            const int col = cbase + nf * 16 + lrow;
            #pragma unroll
            for (int r = 0; r < 4; ++r) {
                const int row = m0 + wr * 64 + mf * 16 + lkb * 4 + r;
                const float v = acc[mf][nf][r];
                if (slab == 0) outY[(size_t)row * 1024 + 512 + col] = v;
                else           Vws[(size_t)row * 512 + col] = f2bf(v);
            }
        }
    }
}

// ---------------------------------------------------------------------------
// Kernel 5: windowed attention. One wave per token.
//   logit[t,s] = Y[t] . X[s]   (Y from d_out scratch, X exact f32)
//   Invalid slots (src<0): logit = 0 exactly, no V term.
// The w=15 K-row (src==tt) is the token's own X row -> reused for the concat
// copy into out[...,0:512].
// ---------------------------------------------------------------------------
__global__ __launch_bounds__(256) void attn_win(
    const float* __restrict__ X,
    const unsigned short* __restrict__ Vws,
    float* __restrict__ out)
{
    const int wid = threadIdx.x >> 6;
    const int ln  = threadIdx.x & 63;
    const int tg  = blockIdx.x * 4 + wid;
    const int b   = tg >> 10;
    const int tt  = tg & 1023;

    // Y fragment from d_out[..., 512:1024]
    float q[8];
    {
        const float4* qp = (const float4*)(out + (size_t)tg * 1024 + 512);
        const float4 a = qp[ln * 2];
        const float4 c = qp[ln * 2 + 1];
        q[0] = a.x; q[1] = a.y; q[2] = a.z; q[3] = a.w;
        q[4] = c.x; q[5] = c.y; q[6] = c.z; q[7] = c.w;
    }

    float lw[16];
    float4 x15a, x15b;   // own X row, saved from w=15 for the concat copy
    #pragma unroll
    for (int w = 0; w < WIN; ++w) {
        const int src = tt - (WIN - 1) + w;
        float dot = 0.0f;
        if (src >= 0) {
            const float* xrow = X + (size_t)(b * Tn + src) * Dn + ln * 8;
            const float4 k0 = *(const float4*)xrow;
            const float4 k1 = *(const float4*)(xrow + 4);
            dot = q[0] * k0.x + q[1] * k0.y + q[2] * k0.z + q[3] * k0.w
                + q[4] * k1.x + q[5] * k1.y + q[6] * k1.z + q[7] * k1.w;
            if (w == WIN - 1) { x15a = k0; x15b = k1; }
        }
        #pragma unroll
        for (int st = 32; st > 0; st >>= 1) dot += __shfl_xor(dot, st, 64);
        lw[w] = (src >= 0) ? dot : 0.0f;
    }

    // Concat copy: out[..., 0:512] = X row (reuses the w=15 load)
    {
        float* o0 = out + (size_t)tg * 1024 + ln * 8;
        *(float4*)o0       = x15a;
        *(float4*)(o0 + 4) = x15b;
    }

    float mx = lw[0];
    #pragma unroll
    for (int w = 1; w < WIN; ++w) mx = fmaxf(mx, lw[w]);
    float den = 0.0f;
    float sc[16];
    #pragma unroll
    for (int w = 0; w < WIN; ++w) { sc[w] = expf(lw[w] - mx); den += sc[w]; }
    const float inv = 1.0f / den;

    float acc[8] = {};
    #pragma unroll
    for (int w = 0; w < WIN; ++w) {
        const int src = tt - (WIN - 1) + w;
        if (src >= 0) {
            const float sw = sc[w] * inv;
            const us8 v = *(const us8*)(Vws + (size_t)(b * Tn + src) * Dn + ln * 8);
            #pragma unroll
            for (int j = 0; j < 8; ++j) acc[j] += sw * bf2f(v[j]);
        }
    }

    float* o1 = out + (size_t)tg * 1024 + 512 + ln * 8;
    *(float4*)o1       = make_float4(acc[0], acc[1], acc[2], acc[3]);
    *(float4*)(o1 + 4) = make_float4(acc[4], acc[5], acc[6], acc[7]);
}

// ---------------------------------------------------------------------------
extern "C" void kernel_launch(void* const* d_in, const int* in_sizes, int n_in,
                              void* d_out, int out_size, void* d_ws, size_t ws_size,
                              hipStream_t stream)
{
    const float* X  = (const float*)d_in[0];
    const float* Mw = (const float*)d_in[1];
    const float* Cw = (const float*)d_in[2];
    const float* Vw = (const float*)d_in[3];
    float* out = (float*)d_out;

    // ws layout (26 MB total):
    short* Ap = (short*)d_ws;                                  // 8192*1024 bf16 = 16 MB
    short* Bt = Ap + (size_t)BT * 1024;                        // 1024*1024 bf16 = 2 MB
    unsigned short* Vws = (unsigned short*)(Bt + (size_t)1024 * 1024); // 8 MB

    split_x<<<(BT * 64) / 256, 256, 0, stream>>>(X, Ap);
    g_gemm<<<dim3(8, 8), 256, 0, stream>>>(Mw, Cw, Bt);
    split_v<<<dim3(8, 8), 256, 0, stream>>>(Vw, Bt);
    gemm_mfma<<<512, 256, 0, stream>>>(Ap, Bt, out, Vws);
    attn_win<<<BT / 4, 256, 0, stream>>>(X, Vws, out);
}

// Round 4
// 95.087 us; speedup vs baseline: 2.2664x; 1.3335x over previous
//
#include <hip/hip_runtime.h>
#include <math.h>

// Problem constants (B=8, T=1024, D=512, LEFT=16, RIGHT=0)
constexpr int Bn = 8;
constexpr int Tn = 1024;
constexpr int Dn = 512;
constexpr int BT = Bn * Tn;      // 8192 rows
constexpr int WIN = 16;

typedef short bs8 __attribute__((ext_vector_type(8)));     // 8 bf16 (bit pattern)
typedef unsigned short us8 __attribute__((ext_vector_type(8)));
typedef float fx4 __attribute__((ext_vector_type(4)));

// bf16 helpers (self-contained, RNE)
__device__ inline unsigned short f2bf(float f) {
    unsigned int u = __float_as_uint(f);
    u += 0x7FFFu + ((u >> 16) & 1u);
    return (unsigned short)(u >> 16);
}
__device__ inline float bf2f(unsigned short h) {
    return __uint_as_float(((unsigned int)h) << 16);
}

// ---------------------------------------------------------------------------
// Kernel 1: split X (f32) -> A' bf16 [8192][1024] = [hi | lo]
// ---------------------------------------------------------------------------
__global__ __launch_bounds__(256) void split_x(const float* __restrict__ X,
                                               short* __restrict__ Ap)
{
    const int i = blockIdx.x * 256 + threadIdx.x;   // 524288 threads
    const int m = i >> 6;
    const int kc = (i & 63) * 8;
    const float4* xp = (const float4*)(X + (size_t)m * Dn + kc);
    const float4 x0 = xp[0], x1 = xp[1];
    const float xs[8] = {x0.x, x0.y, x0.z, x0.w, x1.x, x1.y, x1.z, x1.w};
    union { bs8 v; unsigned short u[8]; } hi, lo;
    #pragma unroll
    for (int j = 0; j < 8; ++j) {
        const float x = xs[j];
        const unsigned short h = f2bf(x);
        hi.u[j] = h;
        lo.u[j] = f2bf(x - bf2f(h));
    }
    short* base = Ap + (size_t)m * 1024 + kc;
    *(bs8*)base         = hi.v;
    *(bs8*)(base + 512) = lo.v;
}

// ---------------------------------------------------------------------------
// Kernel 2a: split-K partials of G = M @ C^T.
// Gp[kc][b][a] = sum_{j in chunk kc} M[a][j] * C[b][j],  kc in 0..3 (K=128).
// Grid (8,8,4), 256 threads, 64x64 tile, 4x4 per thread.
// ---------------------------------------------------------------------------
__global__ __launch_bounds__(256) void g_partial(const float* __restrict__ Mw,
                                                 const float* __restrict__ Cw,
                                                 float* __restrict__ Gp)
{
    __shared__ float As[64][17];   // [a][j]
    __shared__ float Bs[64][17];   // [b][j]
    const int a0 = blockIdx.y * 64;
    const int b0 = blockIdx.x * 64;
    const int kc = blockIdx.z;
    const int tid = threadIdx.x;
    const int tx = tid & 15, ty = tid >> 4;

    float acc[4][4] = {};

    for (int j0 = kc * 128; j0 < kc * 128 + 128; j0 += 16) {
        const int r = tid >> 2;
        const int c = (tid & 3) * 4;
        const float4 a = *(const float4*)(Mw + (size_t)(a0 + r) * Dn + j0 + c);
        As[r][c + 0] = a.x; As[r][c + 1] = a.y; As[r][c + 2] = a.z; As[r][c + 3] = a.w;
        const float4 b = *(const float4*)(Cw + (size_t)(b0 + r) * Dn + j0 + c);
        Bs[r][c + 0] = b.x; Bs[r][c + 1] = b.y; Bs[r][c + 2] = b.z; Bs[r][c + 3] = b.w;
        __syncthreads();
        #pragma unroll
        for (int kk = 0; kk < 16; ++kk) {
            float av[4], bv[4];
            #pragma unroll
            for (int i = 0; i < 4; ++i) av[i] = As[ty * 4 + i][kk];
            #pragma unroll
            for (int j = 0; j < 4; ++j) bv[j] = Bs[tx * 4 + j][kk];
            #pragma unroll
            for (int i = 0; i < 4; ++i)
                #pragma unroll
                for (int j = 0; j < 4; ++j)
                    acc[i][j] += av[i] * bv[j];
        }
        __syncthreads();
    }

    // Write transposed partials: Gp[kc][b][a], float4 along a
    #pragma unroll
    for (int j = 0; j < 4; ++j) {
        const int b = b0 + tx * 4 + j;
        float4 col = make_float4(acc[0][j], acc[1][j], acc[2][j], acc[3][j]);
        *(float4*)(Gp + ((size_t)kc * 512 + b) * 512 + a0 + ty * 4) = col;
    }
}

// ---------------------------------------------------------------------------
// Kernel 2b: pack G = sum of 4 partials, split hi/lo into Bt rows [0,512):
// Bt[b][a] = hi(G[a][b]), Bt[b][512+a] = lo.
// ---------------------------------------------------------------------------
__global__ __launch_bounds__(256) void pack_g(const float* __restrict__ Gp,
                                              short* __restrict__ Bt)
{
    const int i = blockIdx.x * 256 + threadIdx.x;   // 32768 threads
    const int b = i >> 6;
    const int a8 = (i & 63) * 8;
    float s[8] = {};
    #pragma unroll
    for (int kc = 0; kc < 4; ++kc) {
        const float* p = Gp + ((size_t)kc * 512 + b) * 512 + a8;
        const float4 p0 = *(const float4*)p;
        const float4 p1 = *(const float4*)(p + 4);
        s[0] += p0.x; s[1] += p0.y; s[2] += p0.z; s[3] += p0.w;
        s[4] += p1.x; s[5] += p1.y; s[6] += p1.z; s[7] += p1.w;
    }
    union { bs8 v; unsigned short u[8]; } hi, lo;
    #pragma unroll
    for (int j = 0; j < 8; ++j) {
        const unsigned short h = f2bf(s[j]);
        hi.u[j] = h;
        lo.u[j] = f2bf(s[j] - bf2f(h));
    }
    short* base = Bt + (size_t)b * 1024 + a8;
    *(bs8*)base         = hi.v;
    *(bs8*)(base + 512) = lo.v;
}

// ---------------------------------------------------------------------------
// Kernel 3: split+transpose V weights (hi only) -> Bt rows [512,1024):
// Bt[512+n][k] = hi(V[k][n]).  (lo half of these rows is never read.)
// ---------------------------------------------------------------------------
__global__ __launch_bounds__(256) void split_v(const float* __restrict__ Vw,
                                               short* __restrict__ Bt)
{
    __shared__ float tile[64][65];
    const int k0 = blockIdx.x * 64;
    const int n0 = blockIdx.y * 64;
    const int tid = threadIdx.x;

    #pragma unroll
    for (int rr = 0; rr < 4; ++rr) {
        const int row = (tid >> 4) * 4 + rr;        // k
        const int col = (tid & 15) * 4;             // n
        const float4 w = *(const float4*)(Vw + (size_t)(k0 + row) * Dn + n0 + col);
        tile[row][col + 0] = w.x; tile[row][col + 1] = w.y;
        tile[row][col + 2] = w.z; tile[row][col + 3] = w.w;
    }
    __syncthreads();

    const int n  = tid >> 2;          // 0..63
    const int ks = (tid & 3) * 16;    // 0,16,32,48
    union { bs8 v; unsigned short u[8]; } hi0, hi1;
    #pragma unroll
    for (int i = 0; i < 8; ++i) {
        hi0.u[i] = f2bf(tile[ks + i][n]);
        hi1.u[i] = f2bf(tile[ks + 8 + i][n]);
    }
    short* base = Bt + (size_t)(512 + n0 + n) * 1024 + k0 + ks;
    *(bs8*)base       = hi0.v;
    *(bs8*)(base + 8) = hi1.v;
}

// ---------------------------------------------------------------------------
// Kernel 4: bf16 MFMA GEMM, double-buffered LDS (T3-minimal 2-phase).
//   [Y | V'] = X @ [G | V]
//   Y slab (n' in [0,512)):  K' = 1536 = AhiGhi + AloGhi + AhiGlo -> f32
//   V slab (n' in [512,1024)): K' = 512 = AhiVhi -> bf16
// 128x128 tile, BK=32, 4 waves x (64x64), mfma_f32_16x16x32_bf16.
// Per iteration: STAGE(next tile, other buffer) -> ds_read+MFMA(current) ->
// __syncthreads (vmcnt drain covered by the compute).  2x unrolled so buffer
// indices are compile-time constants.
// ---------------------------------------------------------------------------
__global__ __launch_bounds__(256) void gemm_mfma(
    const short* __restrict__ Ap, const short* __restrict__ Bt,
    float* __restrict__ outY, unsigned short* __restrict__ Vws)
{
    __shared__ short Asl[2][128 * 32];   // 2 x 8 KB
    __shared__ short Bsl[2][128 * 32];

    const int lin = blockIdx.x;              // 0..511
    const int xcd = lin & 7;
    const int s   = lin >> 3;                // 0..63
    const int nt  = lin >> 6;                // 0..7 (Y blocks at low lin)
    const int mt  = xcd * 8 + (s & 7);       // 0..63
    const int m0 = mt * 128, n0g = nt * 128;
    const int slab = nt >> 2;                // 0=Y, 1=V
    const int kEnd = slab ? 512 : 1536;

    const int tid = threadIdx.x;
    const int ln  = tid & 63;
    const int wid = tid >> 6;
    const int wr = wid >> 1, wc = wid & 1;
    const int lrow = ln & 15;
    const int lkb  = ln >> 4;                 // 0..3
    const int jsw  = lkb ^ (lrow & 3);        // swizzled chunk sub-index

    fx4 acc[4][4] = {};

    int am[2], aj[2];
    size_t abase[2], bbase[2];
    #pragma unroll
    for (int h = 0; h < 2; ++h) {
        const int c = tid + h * 256;
        am[h] = c >> 2;
        aj[h] = (c & 3) ^ (am[h] & 3);        // kb actually staged
        abase[h] = (size_t)(m0  + am[h]) * 1024 + aj[h] * 8;
        bbase[h] = (size_t)(n0g + am[h]) * 1024 + aj[h] * 8;
    }

    auto stage = [&](int bi, int k0s) {
        const int ka0 = (k0s < 1024) ? k0s : (k0s - 1024);   // A: hi,lo,hi
        const int kb0 = (k0s < 512)  ? k0s : (k0s - 512);    // B: hi,hi,lo
        #pragma unroll
        for (int h = 0; h < 2; ++h) {
            const int c = tid + h * 256;
            __builtin_amdgcn_global_load_lds(
                (const __attribute__((address_space(1))) unsigned int*)(Ap + abase[h] + ka0),
                (__attribute__((address_space(3))) unsigned int*)(&Asl[bi][c * 8]), 16, 0, 0);
            __builtin_amdgcn_global_load_lds(
                (const __attribute__((address_space(1))) unsigned int*)(Bt + bbase[h] + kb0),
                (__attribute__((address_space(3))) unsigned int*)(&Bsl[bi][c * 8]), 16, 0, 0);
        }
    };

    auto compute = [&](const short* As_, const short* Bs_) {
        bs8 a[4], b[4];
        #pragma unroll
        for (int mf = 0; mf < 4; ++mf) {
            const int m = wr * 64 + mf * 16 + lrow;
            a[mf] = *(const bs8*)(As_ + (m * 4 + jsw) * 8);
        }
        #pragma unroll
        for (int nf = 0; nf < 4; ++nf) {
            const int n = wc * 64 + nf * 16 + lrow;
            b[nf] = *(const bs8*)(Bs_ + (n * 4 + jsw) * 8);
        }
        #pragma unroll
        for (int mf = 0; mf < 4; ++mf)
            #pragma unroll
            for (int nf = 0; nf < 4; ++nf)
                acc[mf][nf] = __builtin_amdgcn_mfma_f32_16x16x32_bf16(
                    a[mf], b[nf], acc[mf][nf], 0, 0, 0);
    };

    stage(0, 0);
    __syncthreads();
    for (int k0 = 0; k0 < kEnd; k0 += 64) {
        stage(1, k0 + 32);           // always valid: k0+32 < kEnd (kEnd mult of 64)
        compute(Asl[0], Bsl[0]);
        __syncthreads();
        if (k0 + 64 < kEnd) stage(0, k0 + 64);
        compute(Asl[1], Bsl[1]);
        __syncthreads();
    }

    const int cbase = (n0g - slab * 512) + wc * 64;
    #pragma unroll
    for (int mf = 0; mf < 4; ++mf) {
        #pragma unroll
        for (int nf = 0; nf < 4; ++nf) {
            const int col = cbase + nf * 16 + lrow;
            #pragma unroll
            for (int r = 0; r < 4; ++r) {
                const int row = m0 + wr * 64 + mf * 16 + lkb * 4 + r;
                const float v = acc[mf][nf][r];
                if (slab == 0) outY[(size_t)row * 1024 + 512 + col] = v;
                else           Vws[(size_t)row * 512 + col] = f2bf(v);
            }
        }
    }
}

// ---------------------------------------------------------------------------
// Kernel 5: windowed attention. One wave per token, XCD-swizzled block ids
// so each batch (1024 tokens) stays on one XCD's L2 (16x K/V row reuse).
//   logit[t,s] = Y[t] . X[s]   (Y from d_out scratch, X exact f32)
//   Invalid slots (src<0): logit = 0 exactly, no V term.
// ---------------------------------------------------------------------------
__global__ __launch_bounds__(256) void attn_win(
    const float* __restrict__ X,
    const unsigned short* __restrict__ Vws,
    float* __restrict__ out)
{
    const int lin = blockIdx.x;                       // 0..2047
    const int swz = (lin & 7) * 256 + (lin >> 3);     // 8 XCDs x 256 blocks
    const int wid = threadIdx.x >> 6;
    const int ln  = threadIdx.x & 63;
    const int tg  = swz * 4 + wid;
    const int b   = tg >> 10;
    const int tt  = tg & 1023;

    // Y fragment from d_out[..., 512:1024]
    float q[8];
    {
        const float4* qp = (const float4*)(out + (size_t)tg * 1024 + 512);
        const float4 a = qp[ln * 2];
        const float4 c = qp[ln * 2 + 1];
        q[0] = a.x; q[1] = a.y; q[2] = a.z; q[3] = a.w;
        q[4] = c.x; q[5] = c.y; q[6] = c.z; q[7] = c.w;
    }

    float lw[16];
    float4 x15a, x15b;   // own X row, saved from w=15 for the concat copy
    #pragma unroll
    for (int w = 0; w < WIN; ++w) {
        const int src = tt - (WIN - 1) + w;
        float dot = 0.0f;
        if (src >= 0) {
            const float* xrow = X + (size_t)(b * Tn + src) * Dn + ln * 8;
            const float4 k0 = *(const float4*)xrow;
            const float4 k1 = *(const float4*)(xrow + 4);
            dot = q[0] * k0.x + q[1] * k0.y + q[2] * k0.z + q[3] * k0.w
                + q[4] * k1.x + q[5] * k1.y + q[6] * k1.z + q[7] * k1.w;
            if (w == WIN - 1) { x15a = k0; x15b = k1; }
        }
        #pragma unroll
        for (int st = 32; st > 0; st >>= 1) dot += __shfl_xor(dot, st, 64);
        lw[w] = (src >= 0) ? dot : 0.0f;
    }

    // Concat copy: out[..., 0:512] = X row (reuses the w=15 load)
    {
        float* o0 = out + (size_t)tg * 1024 + ln * 8;
        *(float4*)o0       = x15a;
        *(float4*)(o0 + 4) = x15b;
    }

    float mx = lw[0];
    #pragma unroll
    for (int w = 1; w < WIN; ++w) mx = fmaxf(mx, lw[w]);
    float den = 0.0f;
    float sc[16];
    #pragma unroll
    for (int w = 0; w < WIN; ++w) { sc[w] = expf(lw[w] - mx); den += sc[w]; }
    const float inv = 1.0f / den;

    float acc[8] = {};
    #pragma unroll
    for (int w = 0; w < WIN; ++w) {
        const int src = tt - (WIN - 1) + w;
        if (src >= 0) {
            const float sw = sc[w] * inv;
            const us8 v = *(const us8*)(Vws + (size_t)(b * Tn + src) * Dn + ln * 8);
            #pragma unroll
            for (int j = 0; j < 8; ++j) acc[j] += sw * bf2f(v[j]);
        }
    }

    float* o1 = out + (size_t)tg * 1024 + 512 + ln * 8;
    *(float4*)o1       = make_float4(acc[0], acc[1], acc[2], acc[3]);
    *(float4*)(o1 + 4) = make_float4(acc[4], acc[5], acc[6], acc[7]);
}

// ---------------------------------------------------------------------------
extern "C" void kernel_launch(void* const* d_in, const int* in_sizes, int n_in,
                              void* d_out, int out_size, void* d_ws, size_t ws_size,
                              hipStream_t stream)
{
    const float* X  = (const float*)d_in[0];
    const float* Mw = (const float*)d_in[1];
    const float* Cw = (const float*)d_in[2];
    const float* Vw = (const float*)d_in[3];
    float* out = (float*)d_out;

    // ws layout (30 MB total):
    short* Ap = (short*)d_ws;                                        // 16 MB
    short* Bt = Ap + (size_t)BT * 1024;                              // 2 MB
    unsigned short* Vws = (unsigned short*)(Bt + (size_t)1024 * 1024); // 8 MB
    float* Gp = (float*)(Vws + (size_t)BT * Dn);                     // 4 MB

    split_x<<<(BT * 64) / 256, 256, 0, stream>>>(X, Ap);
    g_partial<<<dim3(8, 8, 4), 256, 0, stream>>>(Mw, Cw, Gp);
    pack_g<<<128, 256, 0, stream>>>(Gp, Bt);
    split_v<<<dim3(8, 8), 256, 0, stream>>>(Vw, Bt);
    gemm_mfma<<<512, 256, 0, stream>>>(Ap, Bt, out, Vws);
    attn_win<<<2048, 256, 0, stream>>>(X, Vws, out);
}